// Round 7
// baseline (797.607 us; speedup 1.0000x reference)
//
#include <hip/hip_runtime.h>
#include <hip/hip_bf16.h>
#include <math.h>

// Problem constants (fixed by setup_inputs)
#define G_NUM   64
#define N_NODES 512
#define K_NN    16
#define TOTAL   (G_NUM * N_NODES)   // 32768
#define E_TOTAL (TOTAL * K_NN)      // 524288
#define D0 4
#define D1 64
#define D2 128
#define D3 256

typedef _Float16 half8  __attribute__((ext_vector_type(8)));
typedef _Float16 half4t __attribute__((ext_vector_type(4)));
typedef _Float16 half2t __attribute__((ext_vector_type(2)));
typedef float    f32x4  __attribute__((ext_vector_type(4)));

// ---------------------------------------------------------------------------
// Kernel 0: prepack W2 [128][64] and W3 [256][128] to f16 in ws (row-major).
// ---------------------------------------------------------------------------
__global__ __launch_bounds__(256) void prepack_kernel(const float* __restrict__ W2,
                                                      const float* __restrict__ W3,
                                                      _Float16* __restrict__ wsh) {
    const int i = blockIdx.x * 256 + threadIdx.x;
    if (i < D2 * D1) wsh[i] = (_Float16)W2[i];                     // 8192
    const int j = i - D2 * D1;
    if (j >= 0 && j < D3 * D2) wsh[D2 * D1 + j] = (_Float16)W3[j]; // 32768
}

// ---------------------------------------------------------------------------
// Kernel 1: per-graph Euclidean KNN (k=16, no self-loop, ties -> lower index).
// UNCHANGED from round 5 (held constant; launched 5x this round to measure
// its duration via the total-time delta).
// ---------------------------------------------------------------------------
__global__ __launch_bounds__(128) void knn_kernel(const float* __restrict__ loc,
                                                  float* __restrict__ out_ei) {
    __shared__ float posx[N_NODES];
    __shared__ float posy[N_NODES];
    const int g  = blockIdx.x;
    const int t  = threadIdx.x;
    const int n  = blockIdx.y * 128 + t;

    for (int i = t; i < N_NODES; i += 128) {
        const float* row = loc + (size_t)(g * N_NODES + i) * 10;
        posx[i] = row[6];
        posy[i] = row[7];
    }
    __syncthreads();

    const float px = posx[n];
    const float py = posy[n];

    float dist[K_NN];
    int   idx[K_NN];
#pragma unroll
    for (int j = 0; j < K_NN; ++j) { dist[j] = INFINITY; idx[j] = 0; }

    for (int c = 0; c < N_NODES; ++c) {
        if (c == n) continue;
        const float dx = posx[c] - px;
        const float dy = posy[c] - py;
        const float d  = dx * dx + dy * dy;
        if (d < dist[K_NN - 1]) {
            dist[K_NN - 1] = d;
            idx[K_NN - 1]  = c;
#pragma unroll
            for (int j = K_NN - 1; j > 0; --j) {
                if (dist[j] < dist[j - 1]) {
                    float td = dist[j]; dist[j] = dist[j - 1]; dist[j - 1] = td;
                    int   ti = idx[j];  idx[j]  = idx[j - 1];  idx[j - 1]  = ti;
                }
            }
        }
    }

    const int node  = g * N_NODES + n;
    const size_t eb = (size_t)node * K_NN;
#pragma unroll
    for (int j = 0; j < K_NN; ++j) {
        const int s = g * N_NODES + idx[j];
        out_ei[eb + j]            = (float)s;
        out_ei[E_TOTAL + eb + j]  = (float)node;
    }
}

// ---------------------------------------------------------------------------
// LDS index helpers: linear rows (h1: 64 f16 = 128 B, h2: 128 f16 = 256 B)
// with XOR swizzle on 16B granules -> all b128 reads / b64 writes uniform
// across bank-quads (optimal phase count).
// ---------------------------------------------------------------------------
__device__ __forceinline__ int h1_ix(int r, int c) { return r * 64  + (c ^ ((r & 7) << 3)); }
__device__ __forceinline__ int h2_ix(int r, int c) { return r * 128 + (c ^ ((r & 7) << 3)); }

// ---------------------------------------------------------------------------
// Kernel 2: fused features (deduped, 4 thr/edge) + layer1 (f32 VALU) +
// layers 2,3 (f16 MFMA, operand-swapped). LDS = 25 KB -> ~6 blocks/CU.
// Block = 256 threads (4 waves), tile = 64 edges.
// ---------------------------------------------------------------------------
__global__ __launch_bounds__(256, 4) void mlp_kernel(const float* __restrict__ loc,
                                                     const float* __restrict__ ei_src,
                                                     const float* __restrict__ W1,
                                                     const float* __restrict__ b1,
                                                     const float* __restrict__ b2,
                                                     const float* __restrict__ b3,
                                                     const _Float16* __restrict__ wsh,
                                                     float* __restrict__ out) {
    __shared__ __align__(16) _Float16 h1s[64 * 64];    // 8 KB
    __shared__ __align__(16) _Float16 h2s[64 * 128];   // 16 KB
    __shared__ __align__(16) float    feat[64][4];     // 1 KB

    const int t = threadIdx.x;
    const int w = t >> 6;          // wave 0..3
    const int l = t & 63;          // lane
    const int lr = l & 15;
    const int lq = l >> 4;
    const size_t tile_base = (size_t)blockIdx.x * 64;

    const _Float16* w2h = wsh;                 // [128][64]
    const _Float16* w3h = wsh + D2 * D1;       // [256][128]

    // ---- Phase 0: features, 4 threads per edge (one feature each) ----
    {
        const int e4 = t >> 2;                 // edge 0..63
        const int f  = t & 3;                  // feature 0..3
        const size_t e = tile_base + e4;
        const int src  = (int)ei_src[e];
        const int tgt  = (int)(e >> 4);
        const float* sr = loc + (size_t)src * 10;
        const float* tr = loc + (size_t)tgt * 10;
        const int ix = (f < 2) ? 6 + f : 2 + f;     // {6,7,4,5}
        const float a = sr[ix];
        const float b = tr[ix];
        const float c = sr[8 + (f & 1)];
        float val;
        if (f < 2) val = (a - b) / c;
        else       val = logf(a / b);
        feat[e4][f] = val;
    }
    __syncthreads();

    // ---- Layer 1 (f32): edge = l, wave w computes channels w*16..w*16+15 ----
    {
        const f32x4 fv = *(const f32x4*)&feat[l][0];
#pragma unroll
        for (int u = 0; u < 8; ++u) {
            const int o0 = w * 16 + 2 * u;
            float a0 = b1[o0]     + fv[0] * W1[o0 * 4]     + fv[1] * W1[o0 * 4 + 1]
                                  + fv[2] * W1[o0 * 4 + 2] + fv[3] * W1[o0 * 4 + 3];
            float a1 = b1[o0 + 1] + fv[0] * W1[o0 * 4 + 4] + fv[1] * W1[o0 * 4 + 5]
                                  + fv[2] * W1[o0 * 4 + 6] + fv[3] * W1[o0 * 4 + 7];
            half2t p;
            p[0] = (_Float16)fmaxf(a0, 0.0f);
            p[1] = (_Float16)fmaxf(a1, 0.0f);
            *(half2t*)&h1s[h1_ix(l, o0)] = p;
        }
    }
    __syncthreads();

    // ---- Layer 2 (MFMA, swapped): wave w -> channels [w*32, w*32+32) ----
    {
        f32x4 acc[2][4];   // [ch-tile][edge-tile]
#pragma unroll
        for (int nn = 0; nn < 2; ++nn) {
            const f32x4 bc = *(const f32x4*)&b2[w * 32 + nn * 16 + lq * 4];
#pragma unroll
            for (int m = 0; m < 4; ++m) acc[nn][m] = bc;
        }
#pragma unroll
        for (int kt = 0; kt < 2; ++kt) {
            half8 wf[2];
#pragma unroll
            for (int nn = 0; nn < 2; ++nn)
                wf[nn] = *(const half8*)(w2h + (w * 32 + nn * 16 + lr) * D1 + kt * 32 + lq * 8);
#pragma unroll
            for (int m = 0; m < 4; ++m) {
                const half8 hf = *(const half8*)&h1s[h1_ix(m * 16 + lr, kt * 32 + lq * 8)];
#pragma unroll
                for (int nn = 0; nn < 2; ++nn)
                    acc[nn][m] = __builtin_amdgcn_mfma_f32_16x16x32_f16(wf[nn], hf, acc[nn][m], 0, 0, 0);
            }
        }
        // h2 write: lane owns edge (m*16+lr), 4 consecutive channels
#pragma unroll
        for (int m = 0; m < 4; ++m)
#pragma unroll
            for (int nn = 0; nn < 2; ++nn) {
                half4t p;
#pragma unroll
                for (int r = 0; r < 4; ++r)
                    p[r] = (_Float16)fmaxf(acc[nn][m][r], 0.0f);
                *(half4t*)&h2s[h2_ix(m * 16 + lr, w * 32 + nn * 16 + lq * 4)] = p;
            }
    }
    __syncthreads();

    // ---- Layer 3 (MFMA, swapped): wave w -> channels [w*64, w*64+64) ----
    {
        f32x4 acc[4][4];   // [ch-tile][edge-tile]
#pragma unroll
        for (int nn = 0; nn < 4; ++nn) {
            const f32x4 bc = *(const f32x4*)&b3[w * 64 + nn * 16 + lq * 4];
#pragma unroll
            for (int m = 0; m < 4; ++m) acc[nn][m] = bc;
        }
#pragma unroll
        for (int kt = 0; kt < 4; ++kt) {
            half8 wf[4];
#pragma unroll
            for (int nn = 0; nn < 4; ++nn)
                wf[nn] = *(const half8*)(w3h + (w * 64 + nn * 16 + lr) * D2 + kt * 32 + lq * 8);
#pragma unroll
            for (int m = 0; m < 4; ++m) {
                const half8 hf = *(const half8*)&h2s[h2_ix(m * 16 + lr, kt * 32 + lq * 8)];
#pragma unroll
                for (int nn = 0; nn < 4; ++nn)
                    acc[nn][m] = __builtin_amdgcn_mfma_f32_16x16x32_f16(wf[nn], hf, acc[nn][m], 0, 0, 0);
            }
        }
        // store: lane -> edge (tile_base+m*16+lr), channels (w*64+nn*16+lq*4 ..+3)
#pragma unroll
        for (int m = 0; m < 4; ++m) {
            const size_t e = tile_base + m * 16 + lr;
#pragma unroll
            for (int nn = 0; nn < 4; ++nn) {
                f32x4 v;
#pragma unroll
                for (int r = 0; r < 4; ++r)
                    v[r] = fmaxf(acc[nn][m][r], 0.0f);
                *(f32x4*)(out + e * D3 + w * 64 + nn * 16 + lq * 4) = v;
            }
        }
    }
}

extern "C" void kernel_launch(void* const* d_in, const int* in_sizes, int n_in,
                              void* d_out, int out_size, void* d_ws, size_t ws_size,
                              hipStream_t stream) {
    const float* loc = (const float*)d_in[0];
    const float* W1  = (const float*)d_in[1];
    const float* b1  = (const float*)d_in[2];
    const float* W2  = (const float*)d_in[3];
    const float* b2  = (const float*)d_in[4];
    const float* W3  = (const float*)d_in[5];
    const float* b3  = (const float*)d_in[6];
    float* out = (float*)d_out;

    float* out_ei = out + (size_t)E_TOTAL * D3;     // edge_index region
    _Float16* wsh = (_Float16*)d_ws;                 // f16 weights (80 KB)

    hipLaunchKernelGGL(prepack_kernel, dim3(160), dim3(256), 0, stream, W2, W3, wsh);
    // 5x launch: deterministic & idempotent; delta vs next round isolates knn dur.
    for (int rep = 0; rep < 5; ++rep)
        hipLaunchKernelGGL(knn_kernel, dim3(G_NUM, 4), dim3(128), 0, stream, loc, out_ei);
    hipLaunchKernelGGL(mlp_kernel, dim3(E_TOTAL / 64), dim3(256), 0, stream,
                       loc, out_ei, W1, b1, b2, b3, wsh, out);
}

// Round 8
// 209.362 us; speedup vs baseline: 3.8097x; 3.8097x over previous
//
#include <hip/hip_runtime.h>
#include <hip/hip_bf16.h>
#include <math.h>

// Problem constants (fixed by setup_inputs)
#define G_NUM   64
#define N_NODES 512
#define K_NN    16
#define TOTAL   (G_NUM * N_NODES)   // 32768
#define E_TOTAL (TOTAL * K_NN)      // 524288
#define D0 4
#define D1 64
#define D2 128
#define D3 256

typedef _Float16 half8  __attribute__((ext_vector_type(8)));
typedef _Float16 half4t __attribute__((ext_vector_type(4)));
typedef _Float16 half2t __attribute__((ext_vector_type(2)));
typedef float    f32x4  __attribute__((ext_vector_type(4)));

// ---------------------------------------------------------------------------
// Kernel 0: prepack W2 [128][64] and W3 [256][128] to f16 in ws (row-major).
// ---------------------------------------------------------------------------
__global__ __launch_bounds__(256) void prepack_kernel(const float* __restrict__ W2,
                                                      const float* __restrict__ W3,
                                                      _Float16* __restrict__ wsh) {
    const int i = blockIdx.x * 256 + threadIdx.x;
    if (i < D2 * D1) wsh[i] = (_Float16)W2[i];                     // 8192
    const int j = i - D2 * D1;
    if (j >= 0 && j < D3 * D2) wsh[D2 * D1 + j] = (_Float16)W3[j]; // 32768
}

// ---------------------------------------------------------------------------
// Kernel 1: parallel per-graph KNN. 8 threads per node: each scans a
// 64-candidate chunk keeping a sorted top-16 in registers (stable, strict <),
// then the 8 lanes (same wave) merge via packed-u64 keys in LDS + shfl_xor
// butterfly min-reduce. Key = (f32_bits(d2)<<32)|c : monotonic in d2 (d2>=0),
// ties -> lower index, exactly matching stable lax.top_k.
// grid = (64 graphs, 16 node-blocks), block = 256 (32 nodes x 8 chunks).
// ---------------------------------------------------------------------------
__global__ __launch_bounds__(256) void knn_kernel(const float* __restrict__ loc,
                                                  float* __restrict__ out_ei) {
    __shared__ float posx[N_NODES];
    __shared__ float posy[N_NODES];
    __shared__ unsigned long long keys[32][8][17];   // pad 17 -> no bank conflicts

    const int g  = blockIdx.x;
    const int nb = blockIdx.y;
    const int t  = threadIdx.x;

    // stage all 512 positions of this graph
    for (int i = t; i < N_NODES; i += 256) {
        const float* row = loc + (size_t)(g * N_NODES + i) * 10;
        posx[i] = row[6];
        posy[i] = row[7];
    }
    __syncthreads();

    const int ng = t >> 3;            // node group within block: 0..31
    const int ch = t & 7;             // chunk: 0..7
    const int n  = nb * 32 + ng;      // node within graph

    const float px = posx[n];
    const float py = posy[n];

    // local sorted top-16 over candidates [ch*64, ch*64+64)
    float dist[K_NN];
    int   idx[K_NN];
#pragma unroll
    for (int j = 0; j < K_NN; ++j) { dist[j] = INFINITY; idx[j] = 0; }

    const int c0 = ch * 64;
    for (int cc = 0; cc < 64; ++cc) {
        const int c = c0 + cc;
        if (c == n) continue;                       // bt_self_loop=False
        const float dx = posx[c] - px;
        const float dy = posy[c] - py;
        const float d  = dx * dx + dy * dy;
        if (d < dist[K_NN - 1]) {                   // strict <  (stable)
            dist[K_NN - 1] = d;
            idx[K_NN - 1]  = c;
#pragma unroll
            for (int j = K_NN - 1; j > 0; --j) {
                if (dist[j] < dist[j - 1]) {
                    float td = dist[j]; dist[j] = dist[j - 1]; dist[j - 1] = td;
                    int   ti = idx[j];  idx[j]  = idx[j - 1];  idx[j - 1]  = ti;
                }
            }
        }
    }

    // pack sorted list into LDS as u64 keys
#pragma unroll
    for (int j = 0; j < K_NN; ++j)
        keys[ng][ch][j] = ((unsigned long long)__float_as_uint(dist[j]) << 32)
                          | (unsigned)idx[j];
    __syncthreads();

    // 8-way merge, 16 selection steps; all 8 lanes of a group are in one wave
    int h = 0;
    float srcf[2];                                   // j = ch*2, ch*2+1
    const int node  = g * N_NODES + n;
    const size_t eb = (size_t)node * K_NN;
#pragma unroll
    for (int j = 0; j < K_NN; ++j) {
        unsigned long long mykey = keys[ng][ch][h];
        unsigned long long win = mykey;
#pragma unroll
        for (int m = 1; m < 8; m <<= 1) {
            const unsigned long long o = __shfl_xor(win, m);
            win = (o < win) ? o : win;
        }
        if (mykey == win) ++h;                       // unique key -> one winner
        if ((j >> 1) == ch)
            srcf[j & 1] = (float)(g * N_NODES + (int)(unsigned)(win & 0xffffffffu));
    }
    // each lane writes its 2 src entries + 2 tgt entries
    out_ei[eb + ch * 2]               = srcf[0];
    out_ei[eb + ch * 2 + 1]           = srcf[1];
    out_ei[E_TOTAL + eb + ch * 2]     = (float)node;
    out_ei[E_TOTAL + eb + ch * 2 + 1] = (float)node;
}

// ---------------------------------------------------------------------------
// LDS index helpers: linear rows (h1: 64 f16 = 128 B, h2: 128 f16 = 256 B)
// with XOR swizzle on 16B granules.
// ---------------------------------------------------------------------------
__device__ __forceinline__ int h1_ix(int r, int c) { return r * 64  + (c ^ ((r & 7) << 3)); }
__device__ __forceinline__ int h2_ix(int r, int c) { return r * 128 + (c ^ ((r & 7) << 3)); }

// ---------------------------------------------------------------------------
// Kernel 2: fused features (deduped, 4 thr/edge) + layer1 (f32 VALU) +
// layers 2,3 (f16 MFMA, operand-swapped). LDS = 25 KB. UNCHANGED from round 7.
// ---------------------------------------------------------------------------
__global__ __launch_bounds__(256, 4) void mlp_kernel(const float* __restrict__ loc,
                                                     const float* __restrict__ ei_src,
                                                     const float* __restrict__ W1,
                                                     const float* __restrict__ b1,
                                                     const float* __restrict__ b2,
                                                     const float* __restrict__ b3,
                                                     const _Float16* __restrict__ wsh,
                                                     float* __restrict__ out) {
    __shared__ __align__(16) _Float16 h1s[64 * 64];    // 8 KB
    __shared__ __align__(16) _Float16 h2s[64 * 128];   // 16 KB
    __shared__ __align__(16) float    feat[64][4];     // 1 KB

    const int t = threadIdx.x;
    const int w = t >> 6;          // wave 0..3
    const int l = t & 63;          // lane
    const int lr = l & 15;
    const int lq = l >> 4;
    const size_t tile_base = (size_t)blockIdx.x * 64;

    const _Float16* w2h = wsh;                 // [128][64]
    const _Float16* w3h = wsh + D2 * D1;       // [256][128]

    // ---- Phase 0: features, 4 threads per edge (one feature each) ----
    {
        const int e4 = t >> 2;                 // edge 0..63
        const int f  = t & 3;                  // feature 0..3
        const size_t e = tile_base + e4;
        const int src  = (int)ei_src[e];
        const int tgt  = (int)(e >> 4);
        const float* sr = loc + (size_t)src * 10;
        const float* tr = loc + (size_t)tgt * 10;
        const int ix = (f < 2) ? 6 + f : 2 + f;     // {6,7,4,5}
        const float a = sr[ix];
        const float b = tr[ix];
        const float c = sr[8 + (f & 1)];
        float val;
        if (f < 2) val = (a - b) / c;
        else       val = logf(a / b);
        feat[e4][f] = val;
    }
    __syncthreads();

    // ---- Layer 1 (f32): edge = l, wave w computes channels w*16..w*16+15 ----
    {
        const f32x4 fv = *(const f32x4*)&feat[l][0];
#pragma unroll
        for (int u = 0; u < 8; ++u) {
            const int o0 = w * 16 + 2 * u;
            float a0 = b1[o0]     + fv[0] * W1[o0 * 4]     + fv[1] * W1[o0 * 4 + 1]
                                  + fv[2] * W1[o0 * 4 + 2] + fv[3] * W1[o0 * 4 + 3];
            float a1 = b1[o0 + 1] + fv[0] * W1[o0 * 4 + 4] + fv[1] * W1[o0 * 4 + 5]
                                  + fv[2] * W1[o0 * 4 + 6] + fv[3] * W1[o0 * 4 + 7];
            half2t p;
            p[0] = (_Float16)fmaxf(a0, 0.0f);
            p[1] = (_Float16)fmaxf(a1, 0.0f);
            *(half2t*)&h1s[h1_ix(l, o0)] = p;
        }
    }
    __syncthreads();

    // ---- Layer 2 (MFMA, swapped): wave w -> channels [w*32, w*32+32) ----
    {
        f32x4 acc[2][4];   // [ch-tile][edge-tile]
#pragma unroll
        for (int nn = 0; nn < 2; ++nn) {
            const f32x4 bc = *(const f32x4*)&b2[w * 32 + nn * 16 + lq * 4];
#pragma unroll
            for (int m = 0; m < 4; ++m) acc[nn][m] = bc;
        }
#pragma unroll
        for (int kt = 0; kt < 2; ++kt) {
            half8 wf[2];
#pragma unroll
            for (int nn = 0; nn < 2; ++nn)
                wf[nn] = *(const half8*)(w2h + (w * 32 + nn * 16 + lr) * D1 + kt * 32 + lq * 8);
#pragma unroll
            for (int m = 0; m < 4; ++m) {
                const half8 hf = *(const half8*)&h1s[h1_ix(m * 16 + lr, kt * 32 + lq * 8)];
#pragma unroll
                for (int nn = 0; nn < 2; ++nn)
                    acc[nn][m] = __builtin_amdgcn_mfma_f32_16x16x32_f16(wf[nn], hf, acc[nn][m], 0, 0, 0);
            }
        }
        // h2 write: lane owns edge (m*16+lr), 4 consecutive channels
#pragma unroll
        for (int m = 0; m < 4; ++m)
#pragma unroll
            for (int nn = 0; nn < 2; ++nn) {
                half4t p;
#pragma unroll
                for (int r = 0; r < 4; ++r)
                    p[r] = (_Float16)fmaxf(acc[nn][m][r], 0.0f);
                *(half4t*)&h2s[h2_ix(m * 16 + lr, w * 32 + nn * 16 + lq * 4)] = p;
            }
    }
    __syncthreads();

    // ---- Layer 3 (MFMA, swapped): wave w -> channels [w*64, w*64+64) ----
    {
        f32x4 acc[4][4];   // [ch-tile][edge-tile]
#pragma unroll
        for (int nn = 0; nn < 4; ++nn) {
            const f32x4 bc = *(const f32x4*)&b3[w * 64 + nn * 16 + lq * 4];
#pragma unroll
            for (int m = 0; m < 4; ++m) acc[nn][m] = bc;
        }
#pragma unroll
        for (int kt = 0; kt < 4; ++kt) {
            half8 wf[4];
#pragma unroll
            for (int nn = 0; nn < 4; ++nn)
                wf[nn] = *(const half8*)(w3h + (w * 64 + nn * 16 + lr) * D2 + kt * 32 + lq * 8);
#pragma unroll
            for (int m = 0; m < 4; ++m) {
                const half8 hf = *(const half8*)&h2s[h2_ix(m * 16 + lr, kt * 32 + lq * 8)];
#pragma unroll
                for (int nn = 0; nn < 4; ++nn)
                    acc[nn][m] = __builtin_amdgcn_mfma_f32_16x16x32_f16(wf[nn], hf, acc[nn][m], 0, 0, 0);
            }
        }
        // store: lane -> edge (tile_base+m*16+lr), channels (w*64+nn*16+lq*4 ..+3)
#pragma unroll
        for (int m = 0; m < 4; ++m) {
            const size_t e = tile_base + m * 16 + lr;
#pragma unroll
            for (int nn = 0; nn < 4; ++nn) {
                f32x4 v;
#pragma unroll
                for (int r = 0; r < 4; ++r)
                    v[r] = fmaxf(acc[nn][m][r], 0.0f);
                *(f32x4*)(out + e * D3 + w * 64 + nn * 16 + lq * 4) = v;
            }
        }
    }
}

extern "C" void kernel_launch(void* const* d_in, const int* in_sizes, int n_in,
                              void* d_out, int out_size, void* d_ws, size_t ws_size,
                              hipStream_t stream) {
    const float* loc = (const float*)d_in[0];
    const float* W1  = (const float*)d_in[1];
    const float* b1  = (const float*)d_in[2];
    const float* W2  = (const float*)d_in[3];
    const float* b2  = (const float*)d_in[4];
    const float* W3  = (const float*)d_in[5];
    const float* b3  = (const float*)d_in[6];
    float* out = (float*)d_out;

    float* out_ei = out + (size_t)E_TOTAL * D3;     // edge_index region
    _Float16* wsh = (_Float16*)d_ws;                 // f16 weights (80 KB)

    hipLaunchKernelGGL(prepack_kernel, dim3(160), dim3(256), 0, stream, W2, W3, wsh);
    hipLaunchKernelGGL(knn_kernel, dim3(G_NUM, 16), dim3(256), 0, stream, loc, out_ei);
    hipLaunchKernelGGL(mlp_kernel, dim3(E_TOTAL / 64), dim3(256), 0, stream,
                       loc, out_ei, W1, b1, b2, b3, wsh, out);
}

// Round 9
// 192.684 us; speedup vs baseline: 4.1395x; 1.0866x over previous
//
#include <hip/hip_runtime.h>
#include <hip/hip_bf16.h>
#include <math.h>

// Problem constants (fixed by setup_inputs)
#define G_NUM   64
#define N_NODES 512
#define K_NN    16
#define TOTAL   (G_NUM * N_NODES)   // 32768
#define E_TOTAL (TOTAL * K_NN)      // 524288
#define D0 4
#define D1 64
#define D2 128
#define D3 256

typedef _Float16 half8  __attribute__((ext_vector_type(8)));
typedef _Float16 half4t __attribute__((ext_vector_type(4)));
typedef _Float16 half2t __attribute__((ext_vector_type(2)));
typedef float    f32x4  __attribute__((ext_vector_type(4)));

// ---------------------------------------------------------------------------
// Kernel 0: prepack W2 [128][64] and W3 [256][128] to f16 in ws (row-major).
// ---------------------------------------------------------------------------
__global__ __launch_bounds__(256) void prepack_kernel(const float* __restrict__ W2,
                                                      const float* __restrict__ W3,
                                                      _Float16* __restrict__ wsh) {
    const int i = blockIdx.x * 256 + threadIdx.x;
    if (i < D2 * D1) wsh[i] = (_Float16)W2[i];                     // 8192
    const int j = i - D2 * D1;
    if (j >= 0 && j < D3 * D2) wsh[D2 * D1 + j] = (_Float16)W3[j]; // 32768
}

// ---------------------------------------------------------------------------
// Kernel 1: parallel per-graph KNN (UNCHANGED from round 8). 8 threads/node,
// chunked scan + u64-key shfl_xor butterfly merge. Stable ties like top_k.
// ---------------------------------------------------------------------------
__global__ __launch_bounds__(256) void knn_kernel(const float* __restrict__ loc,
                                                  float* __restrict__ out_ei) {
    __shared__ float posx[N_NODES];
    __shared__ float posy[N_NODES];
    __shared__ unsigned long long keys[32][8][17];   // pad 17 -> no bank conflicts

    const int g  = blockIdx.x;
    const int nb = blockIdx.y;
    const int t  = threadIdx.x;

    for (int i = t; i < N_NODES; i += 256) {
        const float* row = loc + (size_t)(g * N_NODES + i) * 10;
        posx[i] = row[6];
        posy[i] = row[7];
    }
    __syncthreads();

    const int ng = t >> 3;            // node group within block: 0..31
    const int ch = t & 7;             // chunk: 0..7
    const int n  = nb * 32 + ng;      // node within graph

    const float px = posx[n];
    const float py = posy[n];

    float dist[K_NN];
    int   idx[K_NN];
#pragma unroll
    for (int j = 0; j < K_NN; ++j) { dist[j] = INFINITY; idx[j] = 0; }

    const int c0 = ch * 64;
    for (int cc = 0; cc < 64; ++cc) {
        const int c = c0 + cc;
        if (c == n) continue;                       // bt_self_loop=False
        const float dx = posx[c] - px;
        const float dy = posy[c] - py;
        const float d  = dx * dx + dy * dy;
        if (d < dist[K_NN - 1]) {                   // strict <  (stable)
            dist[K_NN - 1] = d;
            idx[K_NN - 1]  = c;
#pragma unroll
            for (int j = K_NN - 1; j > 0; --j) {
                if (dist[j] < dist[j - 1]) {
                    float td = dist[j]; dist[j] = dist[j - 1]; dist[j - 1] = td;
                    int   ti = idx[j];  idx[j]  = idx[j - 1];  idx[j - 1]  = ti;
                }
            }
        }
    }

#pragma unroll
    for (int j = 0; j < K_NN; ++j)
        keys[ng][ch][j] = ((unsigned long long)__float_as_uint(dist[j]) << 32)
                          | (unsigned)idx[j];
    __syncthreads();

    int h = 0;
    float srcf[2];
    const int node  = g * N_NODES + n;
    const size_t eb = (size_t)node * K_NN;
#pragma unroll
    for (int j = 0; j < K_NN; ++j) {
        unsigned long long mykey = keys[ng][ch][h];
        unsigned long long win = mykey;
#pragma unroll
        for (int m = 1; m < 8; m <<= 1) {
            const unsigned long long o = __shfl_xor(win, m);
            win = (o < win) ? o : win;
        }
        if (mykey == win) ++h;
        if ((j >> 1) == ch)
            srcf[j & 1] = (float)(g * N_NODES + (int)(unsigned)(win & 0xffffffffu));
    }
    out_ei[eb + ch * 2]               = srcf[0];
    out_ei[eb + ch * 2 + 1]           = srcf[1];
    out_ei[E_TOTAL + eb + ch * 2]     = (float)node;
    out_ei[E_TOTAL + eb + ch * 2 + 1] = (float)node;
}

// ---------------------------------------------------------------------------
// LDS index helpers (h1/h2 XOR swizzle on 16B granules).
// ---------------------------------------------------------------------------
__device__ __forceinline__ int h1_ix(int r, int c) { return r * 64  + (c ^ ((r & 7) << 3)); }
__device__ __forceinline__ int h2_ix(int r, int c) { return r * 128 + (c ^ ((r & 7) << 3)); }

#define STG_W 264   // f32 stride per staged edge row (264%32=8 -> write 4-way = floor)

// ---------------------------------------------------------------------------
// Kernel 2: fused features + layer1 (f32) + layers 2,3 (f16 MFMA, swapped).
// NEW: output staged through LDS so each global store instruction writes one
// FULL contiguous 1KB edge row (lane l <-> channels 4l..4l+3). 8 rounds x 8
// edges; relu folded into staging write.
// ---------------------------------------------------------------------------
__global__ __launch_bounds__(256) void mlp_kernel(const float* __restrict__ loc,
                                                  const float* __restrict__ ei_src,
                                                  const float* __restrict__ W1,
                                                  const float* __restrict__ b1,
                                                  const float* __restrict__ b2,
                                                  const float* __restrict__ b3,
                                                  const _Float16* __restrict__ wsh,
                                                  float* __restrict__ out) {
    __shared__ __align__(16) _Float16 h1s[64 * 64];    // 8 KB
    __shared__ __align__(16) _Float16 h2s[64 * 128];   // 16 KB
    __shared__ __align__(16) float    feat[64][4];     // 1 KB
    __shared__ __align__(16) float    stg[8][STG_W];   // 8.25 KB staging

    const int t = threadIdx.x;
    const int w = t >> 6;          // wave 0..3
    const int l = t & 63;          // lane
    const int lr = l & 15;
    const int lq = l >> 4;
    const size_t tile_base = (size_t)blockIdx.x * 64;

    const _Float16* w2h = wsh;                 // [128][64]
    const _Float16* w3h = wsh + D2 * D1;       // [256][128]

    // ---- Phase 0: features, 4 threads per edge (one feature each) ----
    {
        const int e4 = t >> 2;                 // edge 0..63
        const int f  = t & 3;                  // feature 0..3
        const size_t e = tile_base + e4;
        const int src  = (int)ei_src[e];
        const int tgt  = (int)(e >> 4);
        const float* sr = loc + (size_t)src * 10;
        const float* tr = loc + (size_t)tgt * 10;
        const int ix = (f < 2) ? 6 + f : 2 + f;     // {6,7,4,5}
        const float a = sr[ix];
        const float b = tr[ix];
        const float c = sr[8 + (f & 1)];
        float val;
        if (f < 2) val = (a - b) / c;
        else       val = logf(a / b);
        feat[e4][f] = val;
    }
    __syncthreads();

    // ---- Layer 1 (f32): edge = l, wave w computes channels w*16..w*16+15 ----
    {
        const f32x4 fv = *(const f32x4*)&feat[l][0];
#pragma unroll
        for (int u = 0; u < 8; ++u) {
            const int o0 = w * 16 + 2 * u;
            float a0 = b1[o0]     + fv[0] * W1[o0 * 4]     + fv[1] * W1[o0 * 4 + 1]
                                  + fv[2] * W1[o0 * 4 + 2] + fv[3] * W1[o0 * 4 + 3];
            float a1 = b1[o0 + 1] + fv[0] * W1[o0 * 4 + 4] + fv[1] * W1[o0 * 4 + 5]
                                  + fv[2] * W1[o0 * 4 + 6] + fv[3] * W1[o0 * 4 + 7];
            half2t p;
            p[0] = (_Float16)fmaxf(a0, 0.0f);
            p[1] = (_Float16)fmaxf(a1, 0.0f);
            *(half2t*)&h1s[h1_ix(l, o0)] = p;
        }
    }
    __syncthreads();

    // ---- Layer 2 (MFMA, swapped): wave w -> channels [w*32, w*32+32) ----
    {
        f32x4 acc[2][4];   // [ch-tile][edge-tile]
#pragma unroll
        for (int nn = 0; nn < 2; ++nn) {
            const f32x4 bc = *(const f32x4*)&b2[w * 32 + nn * 16 + lq * 4];
#pragma unroll
            for (int m = 0; m < 4; ++m) acc[nn][m] = bc;
        }
#pragma unroll
        for (int kt = 0; kt < 2; ++kt) {
            half8 wf[2];
#pragma unroll
            for (int nn = 0; nn < 2; ++nn)
                wf[nn] = *(const half8*)(w2h + (w * 32 + nn * 16 + lr) * D1 + kt * 32 + lq * 8);
#pragma unroll
            for (int m = 0; m < 4; ++m) {
                const half8 hf = *(const half8*)&h1s[h1_ix(m * 16 + lr, kt * 32 + lq * 8)];
#pragma unroll
                for (int nn = 0; nn < 2; ++nn)
                    acc[nn][m] = __builtin_amdgcn_mfma_f32_16x16x32_f16(wf[nn], hf, acc[nn][m], 0, 0, 0);
            }
        }
#pragma unroll
        for (int m = 0; m < 4; ++m)
#pragma unroll
            for (int nn = 0; nn < 2; ++nn) {
                half4t p;
#pragma unroll
                for (int r = 0; r < 4; ++r)
                    p[r] = (_Float16)fmaxf(acc[nn][m][r], 0.0f);
                *(half4t*)&h2s[h2_ix(m * 16 + lr, w * 32 + nn * 16 + lq * 4)] = p;
            }
    }
    __syncthreads();

    // ---- Layer 3 (MFMA, swapped): wave w -> channels [w*64, w*64+64) ----
    f32x4 acc[4][4];   // [ch-tile][edge-tile]
    {
#pragma unroll
        for (int nn = 0; nn < 4; ++nn) {
            const f32x4 bc = *(const f32x4*)&b3[w * 64 + nn * 16 + lq * 4];
#pragma unroll
            for (int m = 0; m < 4; ++m) acc[nn][m] = bc;
        }
#pragma unroll
        for (int kt = 0; kt < 4; ++kt) {
            half8 wf[4];
#pragma unroll
            for (int nn = 0; nn < 4; ++nn)
                wf[nn] = *(const half8*)(w3h + (w * 64 + nn * 16 + lr) * D2 + kt * 32 + lq * 8);
#pragma unroll
            for (int m = 0; m < 4; ++m) {
                const half8 hf = *(const half8*)&h2s[h2_ix(m * 16 + lr, kt * 32 + lq * 8)];
#pragma unroll
                for (int nn = 0; nn < 4; ++nn)
                    acc[nn][m] = __builtin_amdgcn_mfma_f32_16x16x32_f16(wf[nn], hf, acc[nn][m], 0, 0, 0);
            }
        }
    }

    // ---- Store via LDS transpose: 8 rounds x 8 edges; each global store
    //      instruction = one full contiguous 1KB edge row. ----
#pragma unroll
    for (int q = 0; q < 8; ++q) {
        const int mq = q >> 1;                     // compile-time (unrolled)
        __syncthreads();                           // staging free from prev round
        if ((lr >> 3) == (q & 1)) {
            const int j = lr & 7;                  // staged edge slot
#pragma unroll
            for (int nn = 0; nn < 4; ++nn) {
                f32x4 v;
#pragma unroll
                for (int r = 0; r < 4; ++r)
                    v[r] = fmaxf(acc[nn][mq][r], 0.0f);
                *(f32x4*)&stg[j][w * 64 + nn * 16 + lq * 4] = v;
            }
        }
        __syncthreads();
        // wave w stores edges q*8 + {2w, 2w+1}: lane l -> channels 4l..4l+3
#pragma unroll
        for (int jj = 0; jj < 2; ++jj) {
            const int j = w * 2 + jj;
            const size_t e = tile_base + q * 8 + j;
            const f32x4 v = *(const f32x4*)&stg[j][l * 4];
            *(f32x4*)(out + e * D3 + l * 4) = v;
        }
    }
}

extern "C" void kernel_launch(void* const* d_in, const int* in_sizes, int n_in,
                              void* d_out, int out_size, void* d_ws, size_t ws_size,
                              hipStream_t stream) {
    const float* loc = (const float*)d_in[0];
    const float* W1  = (const float*)d_in[1];
    const float* b1  = (const float*)d_in[2];
    const float* W2  = (const float*)d_in[3];
    const float* b2  = (const float*)d_in[4];
    const float* W3  = (const float*)d_in[5];
    const float* b3  = (const float*)d_in[6];
    float* out = (float*)d_out;

    float* out_ei = out + (size_t)E_TOTAL * D3;     // edge_index region
    _Float16* wsh = (_Float16*)d_ws;                 // f16 weights (80 KB)

    hipLaunchKernelGGL(prepack_kernel, dim3(160), dim3(256), 0, stream, W2, W3, wsh);
    hipLaunchKernelGGL(knn_kernel, dim3(G_NUM, 16), dim3(256), 0, stream, loc, out_ei);
    hipLaunchKernelGGL(mlp_kernel, dim3(E_TOTAL / 64), dim3(256), 0, stream,
                       loc, out_ei, W1, b1, b2, b3, wsh, out);
}